// Round 13
// baseline (908.927 us; speedup 1.0000x reference)
//
#include <hip/hip_runtime.h>
#include <hip/hip_bf16.h>

using bf16x8 = __attribute__((ext_vector_type(8))) short;
using f32x4  = __attribute__((ext_vector_type(4))) float;
using u16x8  = __attribute__((ext_vector_type(8))) unsigned short;

static __device__ __forceinline__ unsigned short f2bf(float f) {
    __hip_bfloat16 h = __float2bfloat16(f);
    return *reinterpret_cast<unsigned short*>(&h);
}

__device__ __forceinline__ int lower_bound_i(const int* __restrict__ a, int n, int v) {
    int lo = 0, hi = n;
    while (lo < hi) {
        int mid = (lo + hi) >> 1;
        if (a[mid] < v) lo = mid + 1; else hi = mid;
    }
    return lo;
}

// ===========================================================================
// FAST PATH: fused producer(convert)/consumer(gather) task-pool kernel.
// Per side: 8 slabs of 32 bf16 cols, slice-major emb16[slice][row][32];
// row NROW all-zero (clamp target). Slab = 2.62 MB -> fits XCD L2.
// Gather blocks are XCD-affine (slice = bid&7). Conversion tiles and gather
// chunks are claimed from atomic pools; slab-completion counters gate the
// gathers. Deadlock-free: a block only polls when all prep tasks are claimed
// (claimants are resident & executing). Output independent of claim order.
// ===========================================================================

#define NROW     40960
#define NROWZ    40961
#define NSLICE   8
#define SLICEW   32
#define IDXPAD   64
#define PTROWS   256                       // rows per prep tile
#define TPSLAB   (NROW / PTROWS)           // 160 tiles per slab
#define NSLAB    16
#define PREPT    (NSLAB * TPSLAB)          // 2560 prep tasks
// ctrl: [0]=pcur, [1..16]=cnt[slab], [17..32]=gcur[slab]

// ---------------------------------------------------------------------------
// Misc: idx pad-copies, W1/W2 MFMA packing, seg bounds, slab zero-rows.
__global__ __launch_bounds__(256)
void nnue_misc(const float* __restrict__ W1, const float* __restrict__ W2,
               const int* __restrict__ widx, const int* __restrict__ bidx,
               const int* __restrict__ wbatch, const int* __restrict__ bbatch,
               int* __restrict__ wi2, int* __restrict__ bi2,
               unsigned short* __restrict__ wemb16, unsigned short* __restrict__ bemb16,
               unsigned short* __restrict__ W1p, unsigned short* __restrict__ W2p,
               int* __restrict__ segs, int n_act, int B)
{
    const int nidx4 = (n_act + IDXPAD) >> 2;
    const int I0 = 2 * nidx4;
    const int I1 = I0 + 8192;
    const int I2 = I1 + 1024;
    const int I3 = I2 + 2 * (B + 1);
    const int I4 = I3 + 2 * NSLICE * 8;
    const int stride = gridDim.x * 256;

    for (int t = blockIdx.x * 256 + threadIdx.x; t < I4; t += stride) {
        if (t < I0) {
            const int side = t >= nidx4;
            const int j = side ? t - nidx4 : t;
            const int* __restrict__ srci = side ? bidx : widx;
            int* __restrict__ dsti = side ? bi2 : wi2;
            const int k4 = j << 2;
            int4 o;
            if (k4 + 3 < n_act) o = *(const int4*)(srci + k4);
            else {
                o.x = (k4     < n_act) ? srci[k4]     : 0;
                o.y = (k4 + 1 < n_act) ? srci[k4 + 1] : 0;
                o.z = (k4 + 2 < n_act) ? srci[k4 + 2] : 0;
                o.w = (k4 + 3 < n_act) ? srci[k4 + 3] : 0;
            }
            *(int4*)(dsti + k4) = o;
        } else if (t < I1) {
            // W1p[(f*64+l)*8+i] = bf16(W1[kc*32+(l>>4)*8+i][nc*16+(l&15)]), f=kc*8+nc
            const int u = t - I0;
            const int f = u >> 6, l = u & 63;
            const int kc = f >> 3, nc = f & 7;
            const int krow = kc * 32 + (l >> 4) * 8;
            const int col  = nc * 16 + (l & 15);
            u16x8 o;
            #pragma unroll
            for (int i = 0; i < 8; ++i) o[i] = f2bf(W1[(size_t)(krow + i) * 128 + col]);
            *(u16x8*)(W1p + (size_t)u * 8) = o;
        } else if (t < I2) {
            const int u = t - I1;
            const int f = u >> 6, l = u & 63;
            const int kc = f >> 2, nc = f & 3;
            const int krow = kc * 32 + (l >> 4) * 8;
            const int col  = nc * 16 + (l & 15);
            u16x8 o;
            #pragma unroll
            for (int i = 0; i < 8; ++i) o[i] = f2bf(W2[(size_t)(krow + i) * 64 + col]);
            *(u16x8*)(W2p + (size_t)u * 8) = o;
        } else if (t < I3) {
            const int u = t - I2;
            const int side = u / (B + 1);
            const int b = u - side * (B + 1);
            const int* bat = side ? bbatch : wbatch;
            segs[u] = lower_bound_i(bat, n_act, b);
        } else {
            const int u = t - I3;            // 0..127
            const int slab = u >> 3;
            const int side = slab >> 3;
            const int s = slab & 7;
            unsigned short* dst = (side ? bemb16 : wemb16)
                + ((size_t)s * NROWZ + NROW) * SLICEW + (u & 7) * 4;
            *(ushort4*)dst = make_ushort4(0, 0, 0, 0);
        }
    }
}

// ---------------------------------------------------------------------------
// Fused convert + gather task pool.
__global__ __launch_bounds__(256)
void nnue_fused(const float* __restrict__ wemb, const float* __restrict__ bemb,
                const int* __restrict__ wi2, const int* __restrict__ bi2,
                const int* __restrict__ stm,
                unsigned short* __restrict__ wemb16, unsigned short* __restrict__ bemb16,
                const int* __restrict__ segs, unsigned short* __restrict__ x16,
                int* __restrict__ ctrl, int B, int nchunk)
{
    __shared__ int sh[2];
    const int tid = threadIdx.x;
    const int slice = blockIdx.x & 7;
    int* __restrict__ pcur = ctrl;
    int* __restrict__ cnt  = ctrl + 1;
    int* __restrict__ gcur = ctrl + 17;

    bool accq[2] = {false, false};   // acquire fence done for side 0/1 slab
    bool exh[2]  = {false, false};   // gather pool exhausted for side 0/1

    for (;;) {
        if (tid == 0) {
            int kind = -1, id = -1;
            // 1) prefer own-slice gathers once their slab is converted
            #pragma unroll
            for (int t = 0; t < 2; ++t) {
                if (kind >= 0 || exh[t]) continue;
                const int s = t * 8 + slice;
                if (__hip_atomic_load(&cnt[s], __ATOMIC_RELAXED,
                                      __HIP_MEMORY_SCOPE_AGENT) >= TPSLAB) {
                    const int g = __hip_atomic_fetch_add(&gcur[s], 1, __ATOMIC_RELAXED,
                                                         __HIP_MEMORY_SCOPE_AGENT);
                    if (g < nchunk) { kind = 1 + t; id = g; }
                    else sh[0] = 0;  // placeholder, fixed below
                    if (g >= nchunk) { /* mark exhausted via sh? no */ }
                }
            }
            // re-run exhaustion marking cleanly
            if (kind < 0) {
                const int p = __hip_atomic_fetch_add(pcur, 1, __ATOMIC_RELAXED,
                                                     __HIP_MEMORY_SCOPE_AGENT);
                if (p < PREPT) { kind = 0; id = p; }
            }
            if (kind < 0) kind = 4;     // poll / maybe done; decided below by all
            sh[0] = kind; sh[1] = id;
        }
        __syncthreads();
        const int kind = sh[0], id = sh[1];
        __syncthreads();

        if (kind == 4) {
            // no prep left and no gather claimed this round: check exhaustion
            bool doneAll = true;
            #pragma unroll
            for (int t = 0; t < 2; ++t) {
                if (!exh[t]) {
                    const int s = t * 8 + slice;
                    const int g = __hip_atomic_load(&gcur[s], __ATOMIC_RELAXED,
                                                    __HIP_MEMORY_SCOPE_AGENT);
                    if (g >= nchunk) exh[t] = true; else doneAll = false;
                }
            }
            if (doneAll) return;
            __builtin_amdgcn_s_sleep(32);
            continue;
        }

        if (kind == 0) {
            // ---- prep tile: slab-major ordering
            const int slab = id / TPSLAB;
            const int tile = id - slab * TPSLAB;
            const int sside = slab >> 3, sl = slab & 7;
            const float* __restrict__ src = sside ? bemb : wemb;
            unsigned short* __restrict__ dst =
                (sside ? bemb16 : wemb16) + (size_t)sl * NROWZ * SLICEW;
            const int wave = tid >> 6, lane = tid & 63;
            const int r = lane >> 3, c = lane & 7;
            const int rbase = tile * PTROWS + wave * 64;
            float4 v[8];
            #pragma unroll
            for (int k = 0; k < 8; ++k)
                v[k] = *(const float4*)(src + (size_t)(rbase + k * 8 + r) * 256
                                        + sl * 32 + c * 4);
            #pragma unroll
            for (int k = 0; k < 8; ++k) {
                ushort4 o;
                o.x = f2bf(v[k].x); o.y = f2bf(v[k].y);
                o.z = f2bf(v[k].z); o.w = f2bf(v[k].w);
                *(ushort4*)(dst + (size_t)(rbase + k * 8 + r) * SLICEW + c * 4) = o;
            }
            __syncthreads();
            if (tid == 0)
                __hip_atomic_fetch_add(&cnt[slab], 1, __ATOMIC_RELEASE,
                                       __HIP_MEMORY_SCOPE_AGENT);
        } else {
            // ---- gather chunk (r8-proven structure): side = kind-1
            const int side = kind - 1;
            if (!accq[side]) {
                // one-time acquire: invalidate stale cached slab lines
                __hip_atomic_load(&cnt[side * 8 + slice], __ATOMIC_ACQUIRE,
                                  __HIP_MEMORY_SCOPE_AGENT);
                accq[side] = true;
            }
            const int wave = tid >> 6, lane = tid & 63;
            const int rg = lane >> 2, cl = lane & 3;
            const int b = id * 64 + wave * 16 + rg;
            const int* __restrict__ idxp = side ? bi2 : wi2;
            const unsigned short* __restrict__ sp =
                (side ? bemb16 : wemb16) + (size_t)slice * NROWZ * SLICEW + cl * 8;
            const int* __restrict__ sg = segs + side * (B + 1);
            const int rs = sg[b], re = sg[b + 1];

            int ml = re - rs;
            ml = max(ml, __shfl_xor(ml, 4, 64));
            ml = max(ml, __shfl_xor(ml, 8, 64));
            ml = max(ml, __shfl_xor(ml, 16, 64));
            ml = max(ml, __shfl_xor(ml, 32, 64));
            const int nit = (ml + 7) >> 3;

            float2 ap[4];
            #pragma unroll
            for (int p4 = 0; p4 < 4; ++p4) { ap[p4].x = 0.f; ap[p4].y = 0.f; }

            int base = rs;
            int4 qa = make_int4(0, 0, 0, 0), qb = qa;
            if (nit > 0) {
                qa = *(const int4*)(idxp + base);
                qb = *(const int4*)(idxp + base + 4);
            }
            for (int it = 0; it < nit; ++it) {
                int4 na = qa, nb = qb;
                if (it + 1 < nit) {
                    na = *(const int4*)(idxp + base + 8);
                    nb = *(const int4*)(idxp + base + 12);
                }
                const int rem = re - base;
                int iu[8];
                iu[0] = qa.x; iu[1] = qa.y; iu[2] = qa.z; iu[3] = qa.w;
                iu[4] = qb.x; iu[5] = qb.y; iu[6] = qb.z; iu[7] = qb.w;
                uint4 v[8];
                #pragma unroll
                for (int u = 0; u < 8; ++u) {
                    const int i = (u < rem) ? iu[u] : NROW;
                    v[u] = *(const uint4*)(sp + (size_t)i * SLICEW);
                }
                #pragma unroll
                for (int u = 0; u < 8; ++u) {
                    #pragma unroll
                    for (int p4 = 0; p4 < 4; ++p4) {
                        const unsigned int cc = (&v[u].x)[p4];
                        ap[p4].x += __uint_as_float(cc << 16);
                        ap[p4].y += __uint_as_float(cc & 0xffff0000u);
                    }
                }
                qa = na; qb = nb; base += 8;
            }

            const int off = (stm[b] == 0) ? (side ? 0 : 256) : (side ? 256 : 0);
            u16x8 o;
            #pragma unroll
            for (int p4 = 0; p4 < 4; ++p4) {
                o[2 * p4]     = f2bf(ap[p4].x);
                o[2 * p4 + 1] = f2bf(ap[p4].y);
            }
            *(u16x8*)(x16 + (size_t)b * 512 + off + slice * SLICEW + cl * 8) = o;
        }
    }
}

// ---------------------------------------------------------------------------
// Fused MLP (verified): L1+L2 via bf16 MFMA, L3+out on VALU. 32 rows/block.
__global__ __launch_bounds__(256)
void nnue_mlp16(const unsigned short* __restrict__ x16,
                const unsigned short* __restrict__ W1p, const float* __restrict__ b1,
                const unsigned short* __restrict__ W2p, const float* __restrict__ b2,
                const float* __restrict__ W3, const float* __restrict__ b3,
                const float* __restrict__ Wo, const float* __restrict__ bo,
                float* __restrict__ out, int B)
{
    __shared__ unsigned short h1s[32 * 128];
    __shared__ float h2s[32][68];
    __shared__ float W3s[64 * 32];

    const int tid = threadIdx.x, wave = tid >> 6, lane = tid & 63;
    const int row0 = blockIdx.x * 32;
    const int m = lane & 15, kg = lane >> 4;

    for (int i = tid; i < 64 * 32; i += 256) W3s[i] = W3[i];

    {
        const int wr = wave >> 1, wc = wave & 1;
        f32x4 acc[4] = {{0,0,0,0},{0,0,0,0},{0,0,0,0},{0,0,0,0}};
        const unsigned short* xrow = x16 + (size_t)(row0 + wr * 16 + m) * 512;
        #pragma unroll
        for (int kc = 0; kc < 16; ++kc) {
            const bf16x8 a = *(const bf16x8*)(xrow + kc * 32 + kg * 8);
            #pragma unroll
            for (int nc = 0; nc < 4; ++nc) {
                const bf16x8 bb = *(const bf16x8*)(W1p + (size_t)((kc * 8 + wc * 4 + nc) * 64 + lane) * 8);
                acc[nc] = __builtin_amdgcn_mfma_f32_16x16x32_bf16(a, bb, acc[nc], 0, 0, 0);
            }
        }
        #pragma unroll
        for (int nc = 0; nc < 4; ++nc) {
            const int col = wc * 64 + nc * 16 + m;
            const float bias = b1[col];
            #pragma unroll
            for (int reg = 0; reg < 4; ++reg) {
                const int row = wr * 16 + kg * 4 + reg;
                const float v = fmaxf(acc[nc][reg] + bias, 0.f);
                h1s[row * 128 + (((col >> 3) ^ (row & 15)) << 3) + (col & 7)] = f2bf(v);
            }
        }
    }
    __syncthreads();

    {
        const int mr = wave >> 1, wc2 = wave & 1;
        f32x4 acc2[2] = {{0,0,0,0},{0,0,0,0}};
        const int row = mr * 16 + m;
        #pragma unroll
        for (int kc = 0; kc < 4; ++kc) {
            const int g = (kc * 4 + kg) ^ (row & 15);
            const bf16x8 a = *(const bf16x8*)&h1s[row * 128 + g * 8];
            #pragma unroll
            for (int ncl = 0; ncl < 2; ++ncl) {
                const bf16x8 bb = *(const bf16x8*)(W2p + (size_t)((kc * 4 + wc2 * 2 + ncl) * 64 + lane) * 8);
                acc2[ncl] = __builtin_amdgcn_mfma_f32_16x16x32_bf16(a, bb, acc2[ncl], 0, 0, 0);
            }
        }
        #pragma unroll
        for (int ncl = 0; ncl < 2; ++ncl) {
            const int col2 = wc2 * 32 + ncl * 16 + m;
            const float bias = b2[col2];
            #pragma unroll
            for (int reg = 0; reg < 4; ++reg) {
                const int row2 = mr * 16 + kg * 4 + reg;
                h2s[row2][col2] = fmaxf(acc2[ncl][reg] + bias, 0.f);
            }
        }
    }
    __syncthreads();

    {
        const int col3 = lane & 31, rsel = lane >> 5;
        const int rbase = wave * 8 + rsel * 4;
        float acc3[4];
        const float bias3 = b3[col3];
        #pragma unroll
        for (int ri = 0; ri < 4; ++ri) acc3[ri] = bias3;
        #pragma unroll
        for (int k = 0; k < 64; k += 4) {
            float4 w;
            w.x = W3s[(k + 0) * 32 + col3];
            w.y = W3s[(k + 1) * 32 + col3];
            w.z = W3s[(k + 2) * 32 + col3];
            w.w = W3s[(k + 3) * 32 + col3];
            #pragma unroll
            for (int ri = 0; ri < 4; ++ri) {
                const float4 h = *(const float4*)&h2s[rbase + ri][k];
                acc3[ri] = fmaf(h.x, w.x, fmaf(h.y, w.y, fmaf(h.z, w.z, fmaf(h.w, w.w, acc3[ri]))));
            }
        }
        const float wo = Wo[col3], bo0 = bo[0];
        #pragma unroll
        for (int ri = 0; ri < 4; ++ri) {
            float v = fmaxf(acc3[ri], 0.f) * wo;
            v += __shfl_xor(v, 16, 64);
            v += __shfl_xor(v, 8, 64);
            v += __shfl_xor(v, 4, 64);
            v += __shfl_xor(v, 2, 64);
            v += __shfl_xor(v, 1, 64);
            if (col3 == 0) out[row0 + rbase + ri] = v + bo0;
        }
    }
}

// ===========================================================================
// FALLBACK (f32 path)
// ===========================================================================

__global__ __launch_bounds__(64)
void nnue_accum_f32(const int* __restrict__ widx, const int* __restrict__ bidx,
                    const int* __restrict__ wbatch, const int* __restrict__ bbatch,
                    const int* __restrict__ stm,
                    const float* __restrict__ wemb, const float* __restrict__ bemb,
                    float* __restrict__ x, int n_act)
{
    const int b = blockIdx.x, side = blockIdx.y;
    const int*   __restrict__ idx   = side ? bidx   : widx;
    const int*   __restrict__ batch = side ? bbatch : wbatch;
    const float* __restrict__ emb   = side ? bemb   : wemb;
    const int start = lower_bound_i(batch, n_act, b);
    const int end   = lower_bound_i(batch, n_act, b + 1);
    const int c = threadIdx.x << 2;
    float4 s0 = make_float4(0.f, 0.f, 0.f, 0.f);
    float4 s1 = s0, s2 = s0, s3 = s0;
    int r = start;
    for (; r + 4 <= end; r += 4) {
        const float4 v0 = *(const float4*)(emb + (size_t)idx[r + 0] * 256 + c);
        const float4 v1 = *(const float4*)(emb + (size_t)idx[r + 1] * 256 + c);
        const float4 v2 = *(const float4*)(emb + (size_t)idx[r + 2] * 256 + c);
        const float4 v3 = *(const float4*)(emb + (size_t)idx[r + 3] * 256 + c);
        s0.x += v0.x; s0.y += v0.y; s0.z += v0.z; s0.w += v0.w;
        s1.x += v1.x; s1.y += v1.y; s1.z += v1.z; s1.w += v1.w;
        s2.x += v2.x; s2.y += v2.y; s2.z += v2.z; s2.w += v2.w;
        s3.x += v3.x; s3.y += v3.y; s3.z += v3.z; s3.w += v3.w;
    }
    for (; r < end; ++r) {
        const float4 v0 = *(const float4*)(emb + (size_t)idx[r] * 256 + c);
        s0.x += v0.x; s0.y += v0.y; s0.z += v0.z; s0.w += v0.w;
    }
    s0.x += s1.x + s2.x + s3.x; s0.y += s1.y + s2.y + s3.y;
    s0.z += s1.z + s2.z + s3.z; s0.w += s1.w + s2.w + s3.w;
    const int off = (stm[b] == 0) ? (side ? 0 : 256) : (side ? 256 : 0);
    *(float4*)(x + (size_t)b * 512 + off + c) = s0;
}

__global__ __launch_bounds__(256)
void nnue_layer1_f32(const float* __restrict__ x, const float* __restrict__ W1,
                     const float* __restrict__ b1, float* __restrict__ h1, int B)
{
    __shared__ float xs[16][512];
    const int tid = threadIdx.x;
    const int row0 = blockIdx.x * 16;
    #pragma unroll
    for (int i = 0; i < 8; ++i) {
        const int e = (i * 256 + tid) * 4;
        const int rr = e >> 9, cc = e & 511;
        if (row0 + rr < B)
            *(float4*)&xs[rr][cc] = *(const float4*)(x + (size_t)(row0 + rr) * 512 + cc);
    }
    __syncthreads();
    const int wave = tid >> 6, lane = tid & 63;
    const int j2 = lane * 2, wrow = wave * 4;
    float2 acc[4];
    #pragma unroll
    for (int r2 = 0; r2 < 4; ++r2) { acc[r2].x = b1[j2]; acc[r2].y = b1[j2 + 1]; }
    for (int k = 0; k < 512; k += 4) {
        float4 xv[4];
        #pragma unroll
        for (int r2 = 0; r2 < 4; ++r2) xv[r2] = *(const float4*)&xs[wrow + r2][k];
        #pragma unroll
        for (int kk = 0; kk < 4; ++kk) {
            const float2 w = *(const float2*)(W1 + (size_t)(k + kk) * 128 + j2);
            #pragma unroll
            for (int r2 = 0; r2 < 4; ++r2) {
                const float xvv = (&xv[r2].x)[kk];
                acc[r2].x = fmaf(xvv, w.x, acc[r2].x);
                acc[r2].y = fmaf(xvv, w.y, acc[r2].y);
            }
        }
    }
    #pragma unroll
    for (int r2 = 0; r2 < 4; ++r2) {
        const int row = row0 + wrow + r2;
        if (row < B) {
            float2 o;
            o.x = fmaxf(acc[r2].x, 0.f); o.y = fmaxf(acc[r2].y, 0.f);
            *(float2*)(h1 + (size_t)row * 128 + j2) = o;
        }
    }
}

__global__ __launch_bounds__(256)
void nnue_tail_f32(const float* __restrict__ h1,
                   const float* __restrict__ W2, const float* __restrict__ b2,
                   const float* __restrict__ W3, const float* __restrict__ b3,
                   const float* __restrict__ Wo, const float* __restrict__ bo,
                   float* __restrict__ out, int B)
{
    __shared__ float W2s[128 * 64];
    __shared__ float W3s[64 * 32];
    __shared__ float Wos[32];
    __shared__ float h1row[4][128];
    __shared__ float h2row[4][64];
    const int tid = threadIdx.x;
    for (int i = tid; i < 128 * 64; i += 256) W2s[i] = W2[i];
    for (int i = tid; i < 64 * 32; i += 256)  W3s[i] = W3[i];
    if (tid < 32) Wos[tid] = Wo[tid];
    __syncthreads();
    const int wave = tid >> 6, lane = tid & 63;
    const float bias2 = b2[lane];
    const float bias3 = (lane < 32) ? b3[lane] : 0.f;
    const float wo = (lane < 32) ? Wos[lane] : 0.f;
    const float bo0 = bo[0];
    #pragma unroll 1
    for (int it = 0; it < 8; ++it) {
        const int row = blockIdx.x * 32 + wave * 8 + it;
        if (row >= B) break;
        h1row[wave][lane]      = h1[(size_t)row * 128 + lane];
        h1row[wave][lane + 64] = h1[(size_t)row * 128 + 64 + lane];
        float acc = bias2;
        #pragma unroll 8
        for (int k = 0; k < 128; ++k)
            acc = fmaf(h1row[wave][k], W2s[k * 64 + lane], acc);
        acc = fmaxf(acc, 0.f);
        h2row[wave][lane] = acc;
        float acc3 = 0.f;
        if (lane < 32) {
            acc3 = bias3;
            #pragma unroll 8
            for (int k = 0; k < 64; ++k)
                acc3 = fmaf(h2row[wave][k], W3s[k * 32 + lane], acc3);
            acc3 = fmaxf(acc3, 0.f) * wo;
        }
        #pragma unroll
        for (int sft = 32; sft >= 1; sft >>= 1)
            acc3 += __shfl_xor(acc3, sft, 64);
        if (lane == 0) out[row] = acc3 + bo0;
    }
}

// ===========================================================================

extern "C" void kernel_launch(void* const* d_in, const int* in_sizes, int n_in,
                              void* d_out, int out_size, void* d_ws, size_t ws_size,
                              hipStream_t stream)
{
    const int*   widx   = (const int*)d_in[0];
    const int*   bidx   = (const int*)d_in[1];
    const int*   wbatch = (const int*)d_in[2];
    const int*   bbatch = (const int*)d_in[3];
    const int*   stm    = (const int*)d_in[4];
    const float* wemb   = (const float*)d_in[5];
    const float* bemb   = (const float*)d_in[6];
    const float* W1     = (const float*)d_in[7];
    const float* b1     = (const float*)d_in[8];
    const float* W2     = (const float*)d_in[9];
    const float* b2     = (const float*)d_in[10];
    const float* W3     = (const float*)d_in[11];
    const float* b3     = (const float*)d_in[12];
    const float* Wo     = (const float*)d_in[13];
    const float* bo     = (const float*)d_in[14];

    const int n_act = in_sizes[0];
    const int B     = in_sizes[4];
    const size_t embN = (size_t)in_sizes[5];   // 40960*256

    // workspace layout (fast path)
    const size_t slabN = (size_t)NSLICE * NROWZ * SLICEW;   // u16 per side
    char* p = (char*)d_ws;
    unsigned short* wemb16 = (unsigned short*)p; p += slabN * 2;
    unsigned short* bemb16 = (unsigned short*)p; p += slabN * 2;
    unsigned short* x16    = (unsigned short*)p; p += (size_t)B * 512 * 2;
    unsigned short* W1p    = (unsigned short*)p; p += 65536 * 2;
    unsigned short* W2p    = (unsigned short*)p; p += 8192 * 2;
    int*            segs   = (int*)p;            p += (size_t)2 * (B + 1) * 4;
    int*            wi2    = (int*)p;            p += (size_t)(n_act + IDXPAD) * 4;
    int*            bi2    = (int*)p;            p += (size_t)(n_act + IDXPAD) * 4;
    // align ctrl to 256B
    p = (char*)(((uintptr_t)p + 255) & ~(uintptr_t)255);
    int*            ctrl   = (int*)p;            p += 64 * 4;
    const size_t needed = (size_t)(p - (char*)d_ws);

    const bool fast = (ws_size >= needed) && (B % 64) == 0 &&
                      embN == (size_t)NROW * 256;

    if (fast) {
        hipMemsetAsync(ctrl, 0, 64 * sizeof(int), stream);
        nnue_misc<<<256, 256, 0, stream>>>(W1, W2, widx, bidx, wbatch, bbatch,
                                           wi2, bi2, wemb16, bemb16,
                                           W1p, W2p, segs, n_act, B);
        const int nchunk = B / 64;   // gather tasks per slab
        nnue_fused<<<2048, 256, 0, stream>>>(wemb, bemb, wi2, bi2, stm,
                                             wemb16, bemb16, segs, x16,
                                             ctrl, B, nchunk);
        nnue_mlp16<<<B / 32, 256, 0, stream>>>(x16, W1p, b1, W2p, b2,
                                               W3, b3, Wo, bo, (float*)d_out, B);
    } else {
        float* x  = (float*)d_ws;
        float* h1 = x + (size_t)B * 512;
        dim3 gA(B, 2);
        nnue_accum_f32<<<gA, 64, 0, stream>>>(widx, bidx, wbatch, bbatch, stm,
                                              wemb, bemb, x, n_act);
        nnue_layer1_f32<<<(B + 15) / 16, 256, 0, stream>>>(x, W1, b1, h1, B);
        nnue_tail_f32<<<(B + 31) / 32, 256, 0, stream>>>(h1, W2, b2, W3, b3, Wo, bo,
                                                         (float*)d_out, B);
    }
}

// Round 14
// 66.347 us; speedup vs baseline: 13.6997x; 13.6997x over previous
//
#include <hip/hip_runtime.h>
#include <hip/hip_bf16.h>

using bf16x8 = __attribute__((ext_vector_type(8))) short;
using f32x4  = __attribute__((ext_vector_type(4))) float;
using u16x8  = __attribute__((ext_vector_type(8))) unsigned short;

static __device__ __forceinline__ float bf2f(unsigned short u) {
    union { unsigned int i; float f; } v; v.i = ((unsigned int)u) << 16; return v.f;
}
static __device__ __forceinline__ unsigned short f2bf(float f) {
    __hip_bfloat16 h = __float2bfloat16(f);
    return *reinterpret_cast<unsigned short*>(&h);
}

__device__ __forceinline__ int lower_bound_i(const int* __restrict__ a, int n, int v) {
    int lo = 0, hi = n;
    while (lo < hi) {
        int mid = (lo + hi) >> 1;
        if (a[mid] < v) lo = mid + 1; else hi = mid;
    }
    return lo;
}

// ===========================================================================
// FAST PATH (round-11 best-known configuration, 66.5 us)
// ===========================================================================
// Per side: 8 slabs of 32 bf16 columns, slice-major: emb16[slice][row][32].
// Row NROW of each slab is all-zero (gather clamp target). Slab = 2.62 MB ->
// fits one XCD's 4 MB L2 (accum: XCD = bid&7 = slice).

#define NROW     40960
#define NROWZ    40961
#define NSLICE   8
#define SLICEW   32        // bf16 columns per slice
#define IDXPAD   256       // padding entries on idx copies
#define SLABCH_B 2064      // LDS chunk stride bytes (32 rows * 64B + 16 pad)

// ---------------------------------------------------------------------------
// Prep6: sequential-read LDS-transpose conversion + misc.
// Misc (grid-stride): idx pad-copies, W1/W2 MFMA packing, seg bounds, zero rows.
// Table: unit = (side, 32-row tile), one per block (2560 blocks).
//   reads:  8 x 4KB perfectly sequential float4 loads per block;
//   LDS:    slab-major staging (8 chunks x 2064B, 16.5 KB);
//   writes: per wave 2 slabs x 4 x 512B contiguous bursts (ascending rows).
__global__ __launch_bounds__(256)
void nnue_prep6(const float* __restrict__ wemb, const float* __restrict__ bemb,
                const float* __restrict__ W1, const float* __restrict__ W2,
                const int* __restrict__ widx, const int* __restrict__ bidx,
                const int* __restrict__ wbatch, const int* __restrict__ bbatch,
                unsigned short* __restrict__ wemb16, unsigned short* __restrict__ bemb16,
                int* __restrict__ wi2, int* __restrict__ bi2,
                unsigned short* __restrict__ W1p, unsigned short* __restrict__ W2p,
                int* __restrict__ segs, int n_act, int B)
{
    __shared__ unsigned char ldsb[NSLICE * SLABCH_B];
    const int tid = threadIdx.x;

    // ---- misc (grid-stride over all threads)
    {
        const int nidx4 = (n_act + IDXPAD) >> 2;
        const int I0 = 2 * nidx4;            // idx pad-copies (int4 items)
        const int I1 = I0 + 8192;            // W1p frag items
        const int I2 = I1 + 1024;            // W2p frag items
        const int I3 = I2 + 2 * (B + 1);     // seg bounds
        const int I4 = I3 + 2 * NSLICE * 8;  // zero rows
        const int stride = gridDim.x * 256;
        for (int t = blockIdx.x * 256 + tid; t < I4; t += stride) {
            if (t < I0) {
                const int side = t >= nidx4;
                const int j = side ? t - nidx4 : t;
                const int* __restrict__ srci = side ? bidx : widx;
                int* __restrict__ dsti = side ? bi2 : wi2;
                const int k4 = j << 2;
                int4 o;
                if (k4 + 3 < n_act) o = *(const int4*)(srci + k4);
                else {
                    o.x = (k4     < n_act) ? srci[k4]     : 0;
                    o.y = (k4 + 1 < n_act) ? srci[k4 + 1] : 0;
                    o.z = (k4 + 2 < n_act) ? srci[k4 + 2] : 0;
                    o.w = (k4 + 3 < n_act) ? srci[k4 + 3] : 0;
                }
                *(int4*)(dsti + k4) = o;
            } else if (t < I1) {
                // W1p[(f*64+l)*8+i] = bf16(W1[kc*32+(l>>4)*8+i][nc*16+(l&15)]), f=kc*8+nc
                const int u = t - I0;
                const int f = u >> 6, l = u & 63;
                const int kc = f >> 3, nc = f & 7;
                const int krow = kc * 32 + (l >> 4) * 8;
                const int col  = nc * 16 + (l & 15);
                u16x8 o;
                #pragma unroll
                for (int i = 0; i < 8; ++i) o[i] = f2bf(W1[(size_t)(krow + i) * 128 + col]);
                *(u16x8*)(W1p + (size_t)u * 8) = o;
            } else if (t < I2) {
                const int u = t - I1;
                const int f = u >> 6, l = u & 63;
                const int kc = f >> 2, nc = f & 3;
                const int krow = kc * 32 + (l >> 4) * 8;
                const int col  = nc * 16 + (l & 15);
                u16x8 o;
                #pragma unroll
                for (int i = 0; i < 8; ++i) o[i] = f2bf(W2[(size_t)(krow + i) * 64 + col]);
                *(u16x8*)(W2p + (size_t)u * 8) = o;
            } else if (t < I3) {
                const int u = t - I2;
                const int side = u / (B + 1);
                const int b = u - side * (B + 1);
                const int* bat = side ? bbatch : wbatch;
                segs[u] = lower_bound_i(bat, n_act, b);
            } else {
                const int u = t - I3;            // 0..127
                const int slab = u >> 3;         // 0..15
                const int side = slab >> 3;
                const int s = slab & 7;
                unsigned short* dst = (side ? bemb16 : wemb16)
                    + ((size_t)s * NROWZ + NROW) * SLICEW + (u & 7) * 4;
                *(ushort4*)dst = make_ushort4(0, 0, 0, 0);
            }
        }
    }

    // ---- table unit: (side, 32-row tile); 2560 units = gridDim.x
    const int unit = blockIdx.x;
    const int side = unit >= 1280;
    const int rt   = side ? unit - 1280 : unit;
    const float* __restrict__ src = (side ? bemb : wemb) + (size_t)rt * 32 * 256;
    unsigned short* __restrict__ dstb = side ? bemb16 : wemb16;
    const int wave = tid >> 6, lane = tid & 63;

    // Phase A: 8 x 4KB sequential reads, cvt, LDS slab-major write
    #pragma unroll
    for (int k = 0; k < 8; ++k) {
        const int e = k * 256 + tid;          // float4 index in [0, 2048)
        const float4 v = *(const float4*)(src + (size_t)e * 4);
        const int row = e >> 6;               // 64 float4 per 256-f32 row
        const int q   = e & 63;
        const int s   = q >> 3, pos = q & 7;
        ushort4 o;
        o.x = f2bf(v.x); o.y = f2bf(v.y); o.z = f2bf(v.z); o.w = f2bf(v.w);
        *(ushort4*)(ldsb + s * SLABCH_B + row * 64 + pos * 8) = o;
    }
    __syncthreads();

    // Phase B: wave w stores slabs {2w, 2w+1}; 4 x 512B contiguous per slab
    #pragma unroll
    for (int j = 0; j < 2; ++j) {
        const int s = 2 * wave + j;
        #pragma unroll
        for (int i = 0; i < 4; ++i) {
            const int row = i * 8 + (lane >> 3);
            const ushort4 o = *(const ushort4*)(ldsb + s * SLABCH_B + row * 64 + (lane & 7) * 8);
            *(ushort4*)(dstb + ((size_t)s * NROWZ + (size_t)rt * 32 + row) * SLICEW
                        + (lane & 7) * 4) = o;
        }
    }
}

// ---------------------------------------------------------------------------
// Accum16s2: XCD-sliced, balanced 4-lane groups (r8/r9-proven structure),
// inner loop restructured to shift/mask + float2 adds (pk-add friendly).
// bid = side*(nchunk*8) + chunk*8 + slice; XCD = bid&7 = slice; sides
// temporally separated (per-XCD live slab = 2.62 MB, L2-resident).
// Block 256 = 4 waves x 16 batches/wave; group rg=lane>>2 owns one batch,
// lanes cl=lane&3 cover its 64B row-slice (16B each). Zero-row clamp tail.
__global__ __launch_bounds__(256)
void nnue_accum16s2(const int* __restrict__ wi2, const int* __restrict__ bi2,
                    const int* __restrict__ stm,
                    const unsigned short* __restrict__ wemb16,
                    const unsigned short* __restrict__ bemb16,
                    const int* __restrict__ segs,
                    unsigned short* __restrict__ x16, int B, int nchunk)
{
    const int wave = threadIdx.x >> 6, lane = threadIdx.x & 63;
    const int slice = blockIdx.x & 7;
    const int rest  = blockIdx.x >> 3;
    const int side  = (rest >= nchunk) ? 1 : 0;
    const int chunk = rest - side * nchunk;

    const int rg = lane >> 2, cl = lane & 3;
    const int b  = chunk * 64 + wave * 16 + rg;

    const int* __restrict__ idxp = side ? bi2 : wi2;
    const unsigned short* __restrict__ sp =
        (side ? bemb16 : wemb16) + (size_t)slice * NROWZ * SLICEW + cl * 8;
    const int* __restrict__ sg = segs + side * (B + 1);

    const int rs = sg[b], re = sg[b + 1];

    // wave-max pack count (group id = lane bits 2..5)
    int ml = re - rs;
    ml = max(ml, __shfl_xor(ml, 4, 64));
    ml = max(ml, __shfl_xor(ml, 8, 64));
    ml = max(ml, __shfl_xor(ml, 16, 64));
    ml = max(ml, __shfl_xor(ml, 32, 64));
    const int nit = (ml + 7) >> 3;

    float2 ap[4];
    #pragma unroll
    for (int p = 0; p < 4; ++p) { ap[p].x = 0.f; ap[p].y = 0.f; }

    int base = rs;
    int4 qa = make_int4(0, 0, 0, 0), qb = qa;
    if (nit > 0) {
        qa = *(const int4*)(idxp + base);
        qb = *(const int4*)(idxp + base + 4);
    }
    for (int it = 0; it < nit; ++it) {
        int4 na = qa, nb = qb;
        if (it + 1 < nit) {
            na = *(const int4*)(idxp + base + 8);
            nb = *(const int4*)(idxp + base + 12);
        }
        const int rem = re - base;
        int iu[8];
        iu[0] = qa.x; iu[1] = qa.y; iu[2] = qa.z; iu[3] = qa.w;
        iu[4] = qb.x; iu[5] = qb.y; iu[6] = qb.z; iu[7] = qb.w;
        uint4 v[8];
        #pragma unroll
        for (int u = 0; u < 8; ++u) {
            const int i = (u < rem) ? iu[u] : NROW;   // invalid rows -> zero row
            v[u] = *(const uint4*)(sp + (size_t)i * SLICEW);
        }
        #pragma unroll
        for (int u = 0; u < 8; ++u) {
            #pragma unroll
            for (int p = 0; p < 4; ++p) {
                const unsigned int c = (&v[u].x)[p];
                ap[p].x += __uint_as_float(c << 16);
                ap[p].y += __uint_as_float(c & 0xffff0000u);
            }
        }
        qa = na; qb = nb; base += 8;
    }

    const int off = (stm[b] == 0) ? (side ? 0 : 256) : (side ? 256 : 0);
    u16x8 o;
    #pragma unroll
    for (int p = 0; p < 4; ++p) {
        o[2 * p]     = f2bf(ap[p].x);
        o[2 * p + 1] = f2bf(ap[p].y);
    }
    *(u16x8*)(x16 + (size_t)b * 512 + off + slice * SLICEW + cl * 8) = o;
}

// ---------------------------------------------------------------------------
// Fused MLP: layer1 (512->128) + layer2 (128->64) via bf16 MFMA,
// layer3 (64->32) + output dot on VALU. 32 rows/block, 4 waves. (verified)
__global__ __launch_bounds__(256)
void nnue_mlp16(const unsigned short* __restrict__ x16,
                const unsigned short* __restrict__ W1p, const float* __restrict__ b1,
                const unsigned short* __restrict__ W2p, const float* __restrict__ b2,
                const float* __restrict__ W3, const float* __restrict__ b3,
                const float* __restrict__ Wo, const float* __restrict__ bo,
                float* __restrict__ out, int B)
{
    __shared__ unsigned short h1s[32 * 128];  // bf16, XOR-swizzled 16B granules
    __shared__ float h2s[32][68];             // f32, padded
    __shared__ float W3s[64 * 32];

    const int tid = threadIdx.x, wave = tid >> 6, lane = tid & 63;
    const int row0 = blockIdx.x * 32;
    const int m = lane & 15, kg = lane >> 4;

    for (int i = tid; i < 64 * 32; i += 256) W3s[i] = W3[i];

    // ---- Layer 1: wave (wr, wc) computes rows [16wr,+16) x cols [64wc,+64)
    {
        const int wr = wave >> 1, wc = wave & 1;
        f32x4 acc[4] = {{0,0,0,0},{0,0,0,0},{0,0,0,0},{0,0,0,0}};
        const unsigned short* xrow = x16 + (size_t)(row0 + wr * 16 + m) * 512;
        #pragma unroll
        for (int kc = 0; kc < 16; ++kc) {
            const bf16x8 a = *(const bf16x8*)(xrow + kc * 32 + kg * 8);
            #pragma unroll
            for (int nc = 0; nc < 4; ++nc) {
                const bf16x8 bb = *(const bf16x8*)(W1p + (size_t)((kc * 8 + wc * 4 + nc) * 64 + lane) * 8);
                acc[nc] = __builtin_amdgcn_mfma_f32_16x16x32_bf16(a, bb, acc[nc], 0, 0, 0);
            }
        }
        #pragma unroll
        for (int nc = 0; nc < 4; ++nc) {
            const int col = wc * 64 + nc * 16 + m;
            const float bias = b1[col];
            #pragma unroll
            for (int reg = 0; reg < 4; ++reg) {
                const int row = wr * 16 + kg * 4 + reg;
                const float v = fmaxf(acc[nc][reg] + bias, 0.f);
                h1s[row * 128 + (((col >> 3) ^ (row & 15)) << 3) + (col & 7)] = f2bf(v);
            }
        }
    }
    __syncthreads();

    // ---- Layer 2: wave (mr, wc2): rows [16mr,+16) x cols [32wc2,+32), K=128
    {
        const int mr = wave >> 1, wc2 = wave & 1;
        f32x4 acc2[2] = {{0,0,0,0},{0,0,0,0}};
        const int row = mr * 16 + m;
        #pragma unroll
        for (int kc = 0; kc < 4; ++kc) {
            const int g = (kc * 4 + kg) ^ (row & 15);
            const bf16x8 a = *(const bf16x8*)&h1s[row * 128 + g * 8];
            #pragma unroll
            for (int ncl = 0; ncl < 2; ++ncl) {
                const bf16x8 bb = *(const bf16x8*)(W2p + (size_t)((kc * 4 + wc2 * 2 + ncl) * 64 + lane) * 8);
                acc2[ncl] = __builtin_amdgcn_mfma_f32_16x16x32_bf16(a, bb, acc2[ncl], 0, 0, 0);
            }
        }
        #pragma unroll
        for (int ncl = 0; ncl < 2; ++ncl) {
            const int col2 = wc2 * 32 + ncl * 16 + m;
            const float bias = b2[col2];
            #pragma unroll
            for (int reg = 0; reg < 4; ++reg) {
                const int row2 = mr * 16 + kg * 4 + reg;
                h2s[row2][col2] = fmaxf(acc2[ncl][reg] + bias, 0.f);
            }
        }
    }
    __syncthreads();

    // ---- Layer 3 + output
    {
        const int col3 = lane & 31, rsel = lane >> 5;
        const int rbase = wave * 8 + rsel * 4;
        float acc3[4];
        const float bias3 = b3[col3];
        #pragma unroll
        for (int ri = 0; ri < 4; ++ri) acc3[ri] = bias3;
        #pragma unroll
        for (int k = 0; k < 64; k += 4) {
            float4 w;
            w.x = W3s[(k + 0) * 32 + col3];
            w.y = W3s[(k + 1) * 32 + col3];
            w.z = W3s[(k + 2) * 32 + col3];
            w.w = W3s[(k + 3) * 32 + col3];
            #pragma unroll
            for (int ri = 0; ri < 4; ++ri) {
                const float4 h = *(const float4*)&h2s[rbase + ri][k];
                acc3[ri] = fmaf(h.x, w.x, fmaf(h.y, w.y, fmaf(h.z, w.z, fmaf(h.w, w.w, acc3[ri]))));
            }
        }
        const float wo = Wo[col3], bo0 = bo[0];
        #pragma unroll
        for (int ri = 0; ri < 4; ++ri) {
            float v = fmaxf(acc3[ri], 0.f) * wo;
            v += __shfl_xor(v, 16, 64);
            v += __shfl_xor(v, 8, 64);
            v += __shfl_xor(v, 4, 64);
            v += __shfl_xor(v, 2, 64);
            v += __shfl_xor(v, 1, 64);
            if (col3 == 0) out[row0 + rbase + ri] = v + bo0;
        }
    }
}

// ===========================================================================
// FALLBACK (f32 path, used only if ws_size is too small or shapes differ)
// ===========================================================================

__global__ __launch_bounds__(64)
void nnue_accum_f32(const int* __restrict__ widx, const int* __restrict__ bidx,
                    const int* __restrict__ wbatch, const int* __restrict__ bbatch,
                    const int* __restrict__ stm,
                    const float* __restrict__ wemb, const float* __restrict__ bemb,
                    float* __restrict__ x, int n_act)
{
    const int b = blockIdx.x, side = blockIdx.y;
    const int*   __restrict__ idx   = side ? bidx   : widx;
    const int*   __restrict__ batch = side ? bbatch : wbatch;
    const float* __restrict__ emb   = side ? bemb   : wemb;
    const int start = lower_bound_i(batch, n_act, b);
    const int end   = lower_bound_i(batch, n_act, b + 1);
    const int c = threadIdx.x << 2;
    float4 s0 = make_float4(0.f, 0.f, 0.f, 0.f);
    float4 s1 = s0, s2 = s0, s3 = s0;
    int r = start;
    for (; r + 4 <= end; r += 4) {
        const float4 v0 = *(const float4*)(emb + (size_t)idx[r + 0] * 256 + c);
        const float4 v1 = *(const float4*)(emb + (size_t)idx[r + 1] * 256 + c);
        const float4 v2 = *(const float4*)(emb + (size_t)idx[r + 2] * 256 + c);
        const float4 v3 = *(const float4*)(emb + (size_t)idx[r + 3] * 256 + c);
        s0.x += v0.x; s0.y += v0.y; s0.z += v0.z; s0.w += v0.w;
        s1.x += v1.x; s1.y += v1.y; s1.z += v1.z; s1.w += v1.w;
        s2.x += v2.x; s2.y += v2.y; s2.z += v2.z; s2.w += v2.w;
        s3.x += v3.x; s3.y += v3.y; s3.z += v3.z; s3.w += v3.w;
    }
    for (; r < end; ++r) {
        const float4 v0 = *(const float4*)(emb + (size_t)idx[r] * 256 + c);
        s0.x += v0.x; s0.y += v0.y; s0.z += v0.z; s0.w += v0.w;
    }
    s0.x += s1.x + s2.x + s3.x; s0.y += s1.y + s2.y + s3.y;
    s0.z += s1.z + s2.z + s3.z; s0.w += s1.w + s2.w + s3.w;
    const int off = (stm[b] == 0) ? (side ? 0 : 256) : (side ? 256 : 0);
    *(float4*)(x + (size_t)b * 512 + off + c) = s0;
}

__global__ __launch_bounds__(256)
void nnue_layer1_f32(const float* __restrict__ x, const float* __restrict__ W1,
                     const float* __restrict__ b1, float* __restrict__ h1, int B)
{
    __shared__ float xs[16][512];
    const int tid = threadIdx.x;
    const int row0 = blockIdx.x * 16;
    #pragma unroll
    for (int i = 0; i < 8; ++i) {
        const int e = (i * 256 + tid) * 4;
        const int rr = e >> 9, cc = e & 511;
        if (row0 + rr < B)
            *(float4*)&xs[rr][cc] = *(const float4*)(x + (size_t)(row0 + rr) * 512 + cc);
    }
    __syncthreads();
    const int wave = tid >> 6, lane = tid & 63;
    const int j2 = lane * 2, wrow = wave * 4;
    float2 acc[4];
    #pragma unroll
    for (int r2 = 0; r2 < 4; ++r2) { acc[r2].x = b1[j2]; acc[r2].y = b1[j2 + 1]; }
    for (int k = 0; k < 512; k += 4) {
        float4 xv[4];
        #pragma unroll
        for (int r2 = 0; r2 < 4; ++r2) xv[r2] = *(const float4*)&xs[wrow + r2][k];
        #pragma unroll
        for (int kk = 0; kk < 4; ++kk) {
            const float2 w = *(const float2*)(W1 + (size_t)(k + kk) * 128 + j2);
            #pragma unroll
            for (int r2 = 0; r2 < 4; ++r2) {
                const float xvv = (&xv[r2].x)[kk];
                acc[r2].x = fmaf(xvv, w.x, acc[r2].x);
                acc[r2].y = fmaf(xvv, w.y, acc[r2].y);
            }
        }
    }
    #pragma unroll
    for (int r2 = 0; r2 < 4; ++r2) {
        const int row = row0 + wrow + r2;
        if (row < B) {
            float2 o;
            o.x = fmaxf(acc[r2].x, 0.f); o.y = fmaxf(acc[r2].y, 0.f);
            *(float2*)(h1 + (size_t)row * 128 + j2) = o;
        }
    }
}

__global__ __launch_bounds__(256)
void nnue_tail_f32(const float* __restrict__ h1,
                   const float* __restrict__ W2, const float* __restrict__ b2,
                   const float* __restrict__ W3, const float* __restrict__ b3,
                   const float* __restrict__ Wo, const float* __restrict__ bo,
                   float* __restrict__ out, int B)
{
    __shared__ float W2s[128 * 64];
    __shared__ float W3s[64 * 32];
    __shared__ float Wos[32];
    __shared__ float h1row[4][128];
    __shared__ float h2row[4][64];
    const int tid = threadIdx.x;
    for (int i = tid; i < 128 * 64; i += 256) W2s[i] = W2[i];
    for (int i = tid; i < 64 * 32; i += 256)  W3s[i] = W3[i];
    if (tid < 32) Wos[tid] = Wo[tid];
    __syncthreads();
    const int wave = tid >> 6, lane = tid & 63;
    const float bias2 = b2[lane];
    const float bias3 = (lane < 32) ? b3[lane] : 0.f;
    const float wo = (lane < 32) ? Wos[lane] : 0.f;
    const float bo0 = bo[0];
    #pragma unroll 1
    for (int it = 0; it < 8; ++it) {
        const int row = blockIdx.x * 32 + wave * 8 + it;
        if (row >= B) break;
        h1row[wave][lane]      = h1[(size_t)row * 128 + lane];
        h1row[wave][lane + 64] = h1[(size_t)row * 128 + 64 + lane];
        float acc = bias2;
        #pragma unroll 8
        for (int k = 0; k < 128; ++k)
            acc = fmaf(h1row[wave][k], W2s[k * 64 + lane], acc);
        acc = fmaxf(acc, 0.f);
        h2row[wave][lane] = acc;
        float acc3 = 0.f;
        if (lane < 32) {
            acc3 = bias3;
            #pragma unroll 8
            for (int k = 0; k < 64; ++k)
                acc3 = fmaf(h2row[wave][k], W3s[k * 32 + lane], acc3);
            acc3 = fmaxf(acc3, 0.f) * wo;
        }
        #pragma unroll
        for (int sft = 32; sft >= 1; sft >>= 1)
            acc3 += __shfl_xor(acc3, sft, 64);
        if (lane == 0) out[row] = acc3 + bo0;
    }
}

// ===========================================================================

extern "C" void kernel_launch(void* const* d_in, const int* in_sizes, int n_in,
                              void* d_out, int out_size, void* d_ws, size_t ws_size,
                              hipStream_t stream)
{
    const int*   widx   = (const int*)d_in[0];
    const int*   bidx   = (const int*)d_in[1];
    const int*   wbatch = (const int*)d_in[2];
    const int*   bbatch = (const int*)d_in[3];
    const int*   stm    = (const int*)d_in[4];
    const float* wemb   = (const float*)d_in[5];
    const float* bemb   = (const float*)d_in[6];
    const float* W1     = (const float*)d_in[7];
    const float* b1     = (const float*)d_in[8];
    const float* W2     = (const float*)d_in[9];
    const float* b2     = (const float*)d_in[10];
    const float* W3     = (const float*)d_in[11];
    const float* b3     = (const float*)d_in[12];
    const float* Wo     = (const float*)d_in[13];
    const float* bo     = (const float*)d_in[14];

    const int n_act = in_sizes[0];
    const int B     = in_sizes[4];
    const size_t embN = (size_t)in_sizes[5];   // 40960*256

    // workspace layout (fast path)
    const size_t slabN = (size_t)NSLICE * NROWZ * SLICEW;   // u16 per side
    char* p = (char*)d_ws;
    unsigned short* wemb16 = (unsigned short*)p; p += slabN * 2;
    unsigned short* bemb16 = (unsigned short*)p; p += slabN * 2;
    unsigned short* x16    = (unsigned short*)p; p += (size_t)B * 512 * 2;
    unsigned short* W1p    = (unsigned short*)p; p += 65536 * 2;
    unsigned short* W2p    = (unsigned short*)p; p += 8192 * 2;
    int*            segs   = (int*)p;            p += (size_t)2 * (B + 1) * 4;
    int*            wi2    = (int*)p;            p += (size_t)(n_act + IDXPAD) * 4;
    int*            bi2    = (int*)p;            p += (size_t)(n_act + IDXPAD) * 4;
    const size_t needed = (size_t)(p - (char*)d_ws);

    const bool fast = (ws_size >= needed) && (B % 64) == 0 &&
                      embN == (size_t)NROW * 256;

    if (fast) {
        // 2560 table units (2 sides x 1280 32-row tiles), one per block
        nnue_prep6<<<2560, 256, 0, stream>>>(wemb, bemb, W1, W2, widx, bidx,
                                             wbatch, bbatch, wemb16, bemb16,
                                             wi2, bi2, W1p, W2p, segs, n_act, B);
        // bid = side*(nchunk*8) + chunk*8 + slice; XCD = bid&7 = slice
        const int nchunk = B / 64;
        const int nblk = 2 * nchunk * NSLICE;
        nnue_accum16s2<<<nblk, 256, 0, stream>>>(wi2, bi2, stm, wemb16, bemb16,
                                                 segs, x16, B, nchunk);
        nnue_mlp16<<<B / 32, 256, 0, stream>>>(x16, W1p, b1, W2p, b2,
                                               W3, b3, Wo, bo, (float*)d_out, B);
    } else {
        float* x  = (float*)d_ws;
        float* h1 = x + (size_t)B * 512;
        dim3 gA(B, 2);
        nnue_accum_f32<<<gA, 64, 0, stream>>>(widx, bidx, wbatch, bbatch, stm,
                                              wemb, bemb, x, n_act);
        nnue_layer1_f32<<<(B + 15) / 16, 256, 0, stream>>>(x, W1, b1, h1, B);
        nnue_tail_f32<<<(B + 31) / 32, 256, 0, stream>>>(h1, W2, b2, W3, b3, Wo, bo,
                                                         (float*)d_out, B);
    }
}